// Round 10
// baseline (1315.541 us; speedup 1.0000x reference)
//
#include <hip/hip_runtime.h>
#include <hip/hip_fp16.h>
#include <stdint.h>

#define BB 128
#define TT 256
#define DDIM 64
#define NDQ 128                // 128 quad-diag groups = 512 diag slots (511 = dummy)
#define WPB 16                 // waves (batches) per scan block
#define BIGF 1e10f
#define KE 144.2695040889f     // 1/(gamma*ln2)
#define GLN2 0.0069314718056f  // gamma*ln2 (R = R' * GLN2)

// [b][diag][row] layouts (K-scaled domain).
__device__ float g_D[(size_t)BB * 512 * TT];      // D' = K*D
__device__ uint4 g_W4[(size_t)BB * NDQ * TT];     // per row: 4 diags of packed f16x2 {wu, wd}
__device__ float g_shape[BB], g_sumE[BB], g_sumEw[BB];

__device__ __forceinline__ float ex2(float x){ float r; asm("v_exp_f32 %0, %1":"=v"(r):"v"(x)); return r; }
__device__ __forceinline__ float lg2(float x){ float r; asm("v_log_f32 %0, %1":"=v"(r):"v"(x)); return r; }
__device__ __forceinline__ float min3f(float a,float b,float c){ float r; asm("v_min3_f32 %0,%1,%2,%3":"=v"(r):"v"(a),"v"(b),"v"(c)); return r; }

__device__ __forceinline__ uint32_t packw(float a, float b){
    auto h2 = __builtin_amdgcn_cvt_pkrtz(a, b);
    union { decltype(h2) h; uint32_t u; } cv; cv.h = h2; return cv.u;
}
__device__ __forceinline__ float2 unpackw(uint32_t pk){
    union { uint32_t u; __half2 h; } cv; cv.u = pk;
    return __half22float2(cv.h);
}

// ---------------------------------------------------------------------------
// Kernel 1: pairwise squared distances (K-scaled), diagonal layout.
// ---------------------------------------------------------------------------
__global__ __launch_bounds__(256) void dist_kernel(const float* __restrict__ P,
                                                   const float* __restrict__ Q) {
    const int rt = blockIdx.x;
    const int ct = blockIdx.y;
    const int b  = blockIdx.z;
    const int tid = threadIdx.x;

    __shared__ float Pl[64][68];
    __shared__ float Tl[64][68];

    const float* Pbase = P + ((size_t)b * TT + rt * 64) * DDIM;
    const float* Qbase = Q + ((size_t)b * TT + ct * 64) * DDIM;

#pragma unroll
    for (int it = 0; it < 4; ++it) {
        int e = (tid + it * 256) * 4;
        int r = e >> 6;
        int k = e & 63;
        float4 pv = *reinterpret_cast<const float4*>(Pbase + e);
        float4 qv = *reinterpret_cast<const float4*>(Qbase + e);
        Pl[k + 0][r] = pv.x; Pl[k + 1][r] = pv.y; Pl[k + 2][r] = pv.z; Pl[k + 3][r] = pv.w;
        Tl[k + 0][r] = qv.x; Tl[k + 1][r] = qv.y; Tl[k + 2][r] = qv.z; Tl[k + 3][r] = qv.w;
    }
    __syncthreads();

    const int r0 = (tid >> 4) * 4;
    const int c0 = (tid & 15) * 4;

    float acc[4][4] = {};
#pragma unroll
    for (int k = 0; k < 64; ++k) {
        float4 p = *reinterpret_cast<const float4*>(&Pl[k][r0]);
        float4 t = *reinterpret_cast<const float4*>(&Tl[k][c0]);
        float pa[4] = {p.x, p.y, p.z, p.w};
        float ta[4] = {t.x, t.y, t.z, t.w};
#pragma unroll
        for (int a = 0; a < 4; ++a)
#pragma unroll
            for (int c = 0; c < 4; ++c) {
                float df = pa[a] - ta[c];
                acc[a][c] = fmaf(df, df, acc[a][c]);
            }
    }

    float* Dg = g_D + (size_t)b * 512 * TT;
#pragma unroll
    for (int a = 0; a < 4; ++a)
#pragma unroll
        for (int c = 0; c < 4; ++c) {
            int i = rt * 64 + r0 + a;
            int j = ct * 64 + c0 + c;
            Dg[(size_t)(i + j) * TT + i] = acc[a][c] * KE;
        }
    if (rt == 0 && ct == 0) Dg[(size_t)511 * TT + tid] = 0.0f;   // dummy diag
}

// ---------------------------------------------------------------------------
// Kernel 2: fused soft-DTW fwd+bwd. ONE WAVE per batch — but now WPB=16
// independent waves per block (4 per SIMD) so hardware wave-interleaving
// hides each wave's stall cycles. Per-wave code identical to round 9:
// rows 4l..4l+3 per lane, 4 diagonals per iteration, no LDS, no barriers,
// boundary values via shfl with compute slack, f16x2 gradient weights.
// ---------------------------------------------------------------------------
__global__ __launch_bounds__(64 * WPB) void scan_kernel() {
    const int tid  = threadIdx.x;
    const int b    = blockIdx.x * WPB + (tid >> 6);
    const int lane = tid & 63;
    const int row0 = lane << 2;
    const bool lane0  = (lane == 0);
    const bool lane63 = (lane == 63);

    const float* Db = g_D  + (size_t)b * 512 * TT;
    uint4*       W4 = g_W4 + (size_t)b * NDQ * TT;

    // ================= forward =================
    float rp1[4], rp2[4];          // own rows' R' at d-1 / d-2
#pragma unroll
    for (int r = 0; r < 4; ++r) { rp1[r] = BIGF; rp2[r] = BIGF; }
    float u1r = BIGF;              // raw shfl: R'[row0-1] at d-1
    float u2v = BIGF;              // selected: R'[row0-1] at d-2

    auto LD = [&](int d) -> float4 {
        return *reinterpret_cast<const float4*>(Db + (size_t)d * TT + row0);
    };

    auto FBODY = [&](float4 (&q)[4], int it) {
        uint32_t wst[4][4];
#pragma unroll
        for (int qq = 0; qq < 4; ++qq) {
            const int d = it * 4 + qq;
            const float dv[4] = {q[qq].x, q[qq].y, q[qq].z, q[qq].w};
            float Rn[4];
#pragma unroll
            for (int r = 1; r < 4; ++r) {
                const float z1 = rp2[r - 1], z2 = rp1[r - 1], z3 = rp1[r];
                const float m  = min3f(z1, z2, z3);
                const float e1 = ex2(m - z1), e2 = ex2(m - z2), e3 = ex2(m - z3);
                const float ss = e1 + e2 + e3;
                const float rv = dv[r] + (m - lg2(ss));
                const float ri = __builtin_amdgcn_rcpf(ss);
                wst[r][qq] = packw(e2 * ri, e1 * ri);
                const bool valid = (unsigned)(d - (row0 + r)) < 256u;
                Rn[r] = valid ? rv : BIGF;
            }
            const float nx = __shfl_up(Rn[3], 1);   // consumed next diag (row0)
            {   // row 0 — consumes boundary values last (shfl slack)
                const float z1 = u2v;
                const float z2 = lane0 ? BIGF : u1r;
                const float z3 = rp1[0];
                const float m  = min3f(z1, z2, z3);
                const float e1 = ex2(m - z1), e2 = ex2(m - z2), e3 = ex2(m - z3);
                const float ss = e1 + e2 + e3;
                float rv = dv[0] + (m - lg2(ss));
                const float ri = __builtin_amdgcn_rcpf(ss);
                wst[0][qq] = packw(e2 * ri, e1 * ri);
                if (d == 0) rv = dv[0];             // R[0][0] = D[0][0]
                const bool valid = (unsigned)(d - row0) < 256u;
                Rn[0] = valid ? rv : BIGF;
            }
#pragma unroll
            for (int r = 0; r < 4; ++r) { rp2[r] = rp1[r]; rp1[r] = Rn[r]; }
            u2v = lane0 ? BIGF : u1r;
            u1r = nx;
        }
#pragma unroll
        for (int r = 0; r < 4; ++r)
            W4[(size_t)it * TT + row0 + r] =
                make_uint4(wst[r][0], wst[r][1], wst[r][2], wst[r][3]);
        const int itn = (it + 2 < NDQ) ? (it + 2) : (NDQ - 1);
#pragma unroll
        for (int qq = 0; qq < 4; ++qq) q[qq] = LD(itn * 4 + qq);
    };

    {
        float4 qa[4], qb[4];
#pragma unroll
        for (int qq = 0; qq < 4; ++qq) { qa[qq] = LD(qq); qb[qq] = LD(4 + qq); }
#pragma unroll 1
        for (int i2 = 0; i2 < 64; ++i2) {
            FBODY(qa, 2 * i2);
            FBODY(qb, 2 * i2 + 1);
        }
    }

    if (lane63) g_shape[b] = rp2[3];   // R'(255, 510)

    asm volatile("s_waitcnt vmcnt(0)" ::: "memory");   // all W stores retired

    // ================= backward =================
    float Ep1[4], Ep2[4];              // E at d+1 / d+2
    float wu1[4], wl1[4];              // weights at d+1
    float wdk1[4], wd2[4];             // wd at d+1 / d+2
#pragma unroll
    for (int r = 0; r < 4; ++r) {
        Ep1[r] = 0.0f; Ep2[r] = 0.0f;
        wu1[r] = 0.0f; wl1[r] = 0.0f; wdk1[r] = 0.0f; wd2[r] = 0.0f;
    }
    float se1r = 0.0f, se2r = 0.0f;    // raw shfl: E[row0+4] at d+1 / d+2
    float su1r = 0.0f;                 // raw shfl: wu[row0+4] at d+1
    float sd1r = 0.0f, sd2r = 0.0f;    // raw shfl: wd[row0+4] at d+1 / d+2
    float sumE = 0.0f, sumEw = 0.0f;

    auto BBODY = [&](uint4 (&wq)[4], int dq) {
#pragma unroll
        for (int qq = 3; qq >= 0; --qq) {
            const int d = dq * 4 + qq;
            float wuc[4], wlc[4], wdc[4];
#pragma unroll
            for (int r = 0; r < 4; ++r) {
                const uint32_t pk = (qq == 0) ? wq[r].x : (qq == 1) ? wq[r].y
                                  : (qq == 2) ? wq[r].z : wq[r].w;
                const float2 wv = unpackw(pk);
                wuc[r] = wv.x; wdc[r] = wv.y; wlc[r] = 1.0f - wv.x - wv.y;
            }
            float En[4];
#pragma unroll
            for (int r = 0; r < 3; ++r)
                En[r] = Ep1[r + 1] * wu1[r + 1] + Ep1[r] * wl1[r]
                      + Ep2[r + 1] * wd2[r + 1];
            const float seN = __shfl_down(En[0], 1);
            const float suN = __shfl_down(wuc[0], 1);
            const float sdN = __shfl_down(wdc[0], 1);
            {   // row 3 — boundary, consumed last (shfl slack)
                const float eu1 = lane63 ? 0.0f : se1r;
                const float wuu = lane63 ? 0.0f : su1r;
                const float eu2 = lane63 ? 0.0f : se2r;
                const float wdu = lane63 ? 0.0f : sd2r;
                En[3] = eu1 * wuu + Ep1[3] * wl1[3] + eu2 * wdu;
            }
            if (d == 510) En[3] = lane63 ? 1.0f : En[3];   // seed (255,255)
#pragma unroll
            for (int r = 0; r < 4; ++r) {
                const bool valid = (unsigned)(d - (row0 + r)) < 256u;
                const float Eg = valid ? En[r] : 0.0f;
                En[r] = Eg;
                sumE += Eg;
                const float fw = (float)(2 * (row0 + r) - d);
                sumEw = fmaf(Eg * fw, fw, sumEw);
            }
#pragma unroll
            for (int r = 0; r < 4; ++r) {
                Ep2[r] = Ep1[r]; Ep1[r] = En[r];
                wu1[r] = wuc[r]; wl1[r] = wlc[r];
                wd2[r] = wdk1[r]; wdk1[r] = wdc[r];
            }
            se2r = se1r; se1r = seN;
            sd2r = sd1r; sd1r = sdN;
            su1r = suN;
        }
        const int dqn = (dq - 2 >= 0) ? (dq - 2) : 0;
#pragma unroll
        for (int r = 0; r < 4; ++r)
            wq[r] = W4[(size_t)dqn * TT + row0 + r];
    };

    {
        uint4 wqa[4], wqb[4];
#pragma unroll
        for (int r = 0; r < 4; ++r) {
            wqa[r] = W4[(size_t)(NDQ - 1) * TT + row0 + r];
            wqb[r] = W4[(size_t)(NDQ - 2) * TT + row0 + r];
        }
#pragma unroll 1
        for (int i2 = 0; i2 < 64; ++i2) {
            BBODY(wqa, 127 - 2 * i2);
            BBODY(wqb, 126 - 2 * i2);
        }
    }

    // wave reduction
#pragma unroll
    for (int off = 32; off; off >>= 1) {
        sumE  += __shfl_xor(sumE,  off);
        sumEw += __shfl_xor(sumEw, off);
    }
    if (lane == 0) { g_sumE[b] = sumE; g_sumEw[b] = sumEw; }
}

// ---------------------------------------------------------------------------
// Kernel 3: finalize scalar loss.
// ---------------------------------------------------------------------------
__global__ __launch_bounds__(128) void fin_kernel(float* __restrict__ out) {
    __shared__ float rs[128];
    __shared__ float rt2[128];
    const int b = threadIdx.x;

    const float shape = g_shape[b] * GLN2 * (1.0f / (float)TT);

    const float sE  = g_sumE[b]  * (1.0f / (float)TT);
    const float sEw = g_sumEw[b] * (1.0f / (float)TT) * (1.0f / (255.0f * 255.0f));
    const float temporal = sEw / fmaxf(sE, 1e-8f);

    rs[b]  = shape;
    rt2[b] = temporal;
    __syncthreads();
    for (int s = 64; s > 0; s >>= 1) {
        if (b < s) { rs[b] += rs[b + s]; rt2[b] += rt2[b + s]; }
        __syncthreads();
    }
    if (b == 0) {
        out[0] = 0.5f * (rs[0] * (1.0f / (float)BB)) + 0.5f * (rt2[0] * (1.0f / (float)BB));
    }
}

extern "C" void kernel_launch(void* const* d_in, const int* in_sizes, int n_in,
                              void* d_out, int out_size, void* d_ws, size_t ws_size,
                              hipStream_t stream) {
    (void)in_sizes; (void)n_in; (void)out_size; (void)d_ws; (void)ws_size;
    const float* preds   = (const float*)d_in[0];
    const float* targets = (const float*)d_in[1];
    float* out = (float*)d_out;

    dist_kernel<<<dim3(4, 4, BB), 256, 0, stream>>>(preds, targets);
    scan_kernel<<<BB / WPB, 64 * WPB, 0, stream>>>();
    fin_kernel<<<1, 128, 0, stream>>>(out);
}

// Round 11
// 191.092 us; speedup vs baseline: 6.8843x; 6.8843x over previous
//
#include <hip/hip_runtime.h>
#include <stdint.h>

#define BB 128
#define TT 256
#define DDIM 64
#define NDQ 128                // 128 quad-diag groups = 512 diag slots (511 = dummy)
#define BIGF 1e10f
#define KE 144.2695040889f     // 1/(gamma*ln2)
#define GLN2 0.0069314718056f  // gamma*ln2 (R = R' * GLN2)

// [b][diag][row] layout (K-scaled domain).
__device__ float g_D[(size_t)BB * 512 * TT];      // D' = K*D
__device__ float g_shape[BB], g_sumE[BB], g_sumEw[BB];

__device__ __forceinline__ float ex2(float x){ float r; asm("v_exp_f32 %0, %1":"=v"(r):"v"(x)); return r; }
__device__ __forceinline__ float lg2(float x){ float r; asm("v_log_f32 %0, %1":"=v"(r):"v"(x)); return r; }
__device__ __forceinline__ float min3f(float a,float b,float c){ float r; asm("v_min3_f32 %0,%1,%2,%3":"=v"(r):"v"(a),"v"(b),"v"(c)); return r; }

// ---------------------------------------------------------------------------
// Kernel 1: pairwise squared distances (K-scaled), diagonal layout.
// ---------------------------------------------------------------------------
__global__ __launch_bounds__(256) void dist_kernel(const float* __restrict__ P,
                                                   const float* __restrict__ Q) {
    const int rt = blockIdx.x;
    const int ct = blockIdx.y;
    const int b  = blockIdx.z;
    const int tid = threadIdx.x;

    __shared__ float Pl[64][68];
    __shared__ float Tl[64][68];

    const float* Pbase = P + ((size_t)b * TT + rt * 64) * DDIM;
    const float* Qbase = Q + ((size_t)b * TT + ct * 64) * DDIM;

#pragma unroll
    for (int it = 0; it < 4; ++it) {
        int e = (tid + it * 256) * 4;
        int r = e >> 6;
        int k = e & 63;
        float4 pv = *reinterpret_cast<const float4*>(Pbase + e);
        float4 qv = *reinterpret_cast<const float4*>(Qbase + e);
        Pl[k + 0][r] = pv.x; Pl[k + 1][r] = pv.y; Pl[k + 2][r] = pv.z; Pl[k + 3][r] = pv.w;
        Tl[k + 0][r] = qv.x; Tl[k + 1][r] = qv.y; Tl[k + 2][r] = qv.z; Tl[k + 3][r] = qv.w;
    }
    __syncthreads();

    const int r0 = (tid >> 4) * 4;
    const int c0 = (tid & 15) * 4;

    float acc[4][4] = {};
#pragma unroll
    for (int k = 0; k < 64; ++k) {
        float4 p = *reinterpret_cast<const float4*>(&Pl[k][r0]);
        float4 t = *reinterpret_cast<const float4*>(&Tl[k][c0]);
        float pa[4] = {p.x, p.y, p.z, p.w};
        float ta[4] = {t.x, t.y, t.z, t.w};
#pragma unroll
        for (int a = 0; a < 4; ++a)
#pragma unroll
            for (int c = 0; c < 4; ++c) {
                float df = pa[a] - ta[c];
                acc[a][c] = fmaf(df, df, acc[a][c]);
            }
    }

    float* Dg = g_D + (size_t)b * 512 * TT;
#pragma unroll
    for (int a = 0; a < 4; ++a)
#pragma unroll
        for (int c = 0; c < 4; ++c) {
            int i = rt * 64 + r0 + a;
            int j = ct * 64 + c0 + c;
            Dg[(size_t)(i + j) * TT + i] = acc[a][c] * KE;
        }
    if (rt == 0 && ct == 0) Dg[(size_t)511 * TT + tid] = 0.0f;   // dummy diag
}

// ---------------------------------------------------------------------------
// Kernel 2: SINGLE-PASS soft-DTW. One wave per batch, rows 4l..4l+3 per lane,
// 4 diagonals per iteration. Alongside R', forward-propagate the path-sum
// accumulators H (seed 1) and G (seed (i-j)^2):
//   H[i,j] = 1 + wu*H[i-1,j] + wl*H[i,j-1] + wd*H[i-1,j-1]
// with wu,wl,wd = softmin gradient weights of cell (i,j). Identity:
//   H[255,255] = sum(E) ,  G[255,255] = sum(E*omega_unscaled)
// so NO backward pass, NO R/W storage. Output: 3 floats per batch.
// ---------------------------------------------------------------------------
__global__ __launch_bounds__(64) void scan_kernel() {
    const int b    = blockIdx.x;
    const int lane = threadIdx.x;
    const int row0 = lane << 2;
    const bool lane0 = (lane == 0);

    const float* Db = g_D + (size_t)b * 512 * TT;

    // per-row state at diag d-1 / d-2
    float rp1[4], rp2[4], h1[4], h2[4], g1[4], g2[4];
#pragma unroll
    for (int r = 0; r < 4; ++r) {
        rp1[r] = BIGF; rp2[r] = BIGF;
        h1[r] = 0.0f;  h2[r] = 0.0f;
        g1[r] = 0.0f;  g2[r] = 0.0f;
    }
    // boundary rings: uX = raw shfl result (neighbor row at d-1),
    //                 uX2 = selected value (neighbor row at d-2)
    float uR = BIGF, uR2 = BIGF;
    float uH = 0.0f, uH2 = 0.0f;
    float uG = 0.0f, uG2 = 0.0f;

    auto LD = [&](int d) -> float4 {
        return *reinterpret_cast<const float4*>(Db + (size_t)d * TT + row0);
    };

    // one cell: z1/Hd/Gd = diag pred (d-2), z2/Hu/Gu = up pred (d-1),
    // z3/Hl/Gl = left pred (d-1)
    auto CELL = [&](int d, int r, float z1, float z2, float z3,
                    float Hd, float Hu, float Hl,
                    float Gd, float Gu, float Gl,
                    float dvv, bool isD0,
                    float& Rn, float& Hn, float& Gn) {
        const float m  = min3f(z1, z2, z3);
        const float e1 = ex2(m - z1);   // diag weight (unnorm)
        const float e2 = ex2(m - z2);   // up
        const float e3 = ex2(m - z3);   // left
        const float ss = e1 + e2 + e3;
        const float ri = __builtin_amdgcn_rcpf(ss);
        float rv = dvv + (m - lg2(ss));
        if (isD0) rv = dvv;                         // R[0][0] = D[0][0]
        const bool valid = (unsigned)(d - (row0 + r)) < 256u;
        Rn = valid ? rv : BIGF;
        float ha = e2 * Hu; ha = fmaf(e3, Hl, ha); ha = fmaf(e1, Hd, ha);
        Hn = valid ? fmaf(ri, ha, 1.0f) : 0.0f;
        const float fw = (float)(d - 2 * (row0 + r));   // -(i-j); squared below
        float ga = e2 * Gu; ga = fmaf(e3, Gl, ga); ga = fmaf(e1, Gd, ga);
        Gn = valid ? fmaf(ri, ga, fw * fw) : 0.0f;
    };

    auto FBODY = [&](float4 (&q)[4], int it) {
#pragma unroll
        for (int qq = 0; qq < 4; ++qq) {
            const int d = it * 4 + qq;
            const float dv[4] = {q[qq].x, q[qq].y, q[qq].z, q[qq].w};
            float Rn[4], Hn[4], Gn[4];
#pragma unroll
            for (int r = 1; r < 4; ++r)
                CELL(d, r, rp2[r - 1], rp1[r - 1], rp1[r],
                     h2[r - 1], h1[r - 1], h1[r],
                     g2[r - 1], g1[r - 1], g1[r],
                     dv[r], false, Rn[r], Hn[r], Gn[r]);
            // issue boundary shuffles; consumed next diag (1 diag of slack)
            const float nR = __shfl_up(Rn[3], 1);
            const float nH = __shfl_up(Hn[3], 1);
            const float nG = __shfl_up(Gn[3], 1);
            {   // row 0 — consumes previous diag's shuffles
                const float z2 = lane0 ? BIGF : uR;
                const float Hu = lane0 ? 0.0f : uH;
                const float Gu = lane0 ? 0.0f : uG;
                CELL(d, 0, uR2, z2, rp1[0],
                     uH2, Hu, h1[0],
                     uG2, Gu, g1[0],
                     dv[0], d == 0, Rn[0], Hn[0], Gn[0]);
            }
#pragma unroll
            for (int r = 0; r < 4; ++r) {
                rp2[r] = rp1[r]; rp1[r] = Rn[r];
                h2[r]  = h1[r];  h1[r]  = Hn[r];
                g2[r]  = g1[r];  g1[r]  = Gn[r];
            }
            uR2 = lane0 ? BIGF : uR;  uR = nR;
            uH2 = lane0 ? 0.0f : uH;  uH = nH;
            uG2 = lane0 ? 0.0f : uG;  uG = nG;
        }
        const int itn = (it + 2 < NDQ) ? (it + 2) : (NDQ - 1);
#pragma unroll
        for (int qq = 0; qq < 4; ++qq) q[qq] = LD(itn * 4 + qq);
    };

    {
        float4 qa[4], qb[4];
#pragma unroll
        for (int qq = 0; qq < 4; ++qq) { qa[qq] = LD(qq); qb[qq] = LD(4 + qq); }
#pragma unroll 1
        for (int i2 = 0; i2 < 64; ++i2) {
            FBODY(qa, 2 * i2);
            FBODY(qb, 2 * i2 + 1);
        }
    }

    // after processing dummy diag 511, the d-2 state holds diag 510
    if (lane == 63) {
        g_shape[b] = rp2[3];   // R'(255,255)
        g_sumE[b]  = h2[3];    // sum(E)
        g_sumEw[b] = g2[3];    // sum(E * (i-j)^2)
    }
}

// ---------------------------------------------------------------------------
// Kernel 3: finalize scalar loss.
// ---------------------------------------------------------------------------
__global__ __launch_bounds__(128) void fin_kernel(float* __restrict__ out) {
    __shared__ float rs[128];
    __shared__ float rt2[128];
    const int b = threadIdx.x;

    const float shape = g_shape[b] * GLN2 * (1.0f / (float)TT);

    const float sE  = g_sumE[b]  * (1.0f / (float)TT);
    const float sEw = g_sumEw[b] * (1.0f / (float)TT) * (1.0f / (255.0f * 255.0f));
    const float temporal = sEw / fmaxf(sE, 1e-8f);

    rs[b]  = shape;
    rt2[b] = temporal;
    __syncthreads();
    for (int s = 64; s > 0; s >>= 1) {
        if (b < s) { rs[b] += rs[b + s]; rt2[b] += rt2[b + s]; }
        __syncthreads();
    }
    if (b == 0) {
        out[0] = 0.5f * (rs[0] * (1.0f / (float)BB)) + 0.5f * (rt2[0] * (1.0f / (float)BB));
    }
}

extern "C" void kernel_launch(void* const* d_in, const int* in_sizes, int n_in,
                              void* d_out, int out_size, void* d_ws, size_t ws_size,
                              hipStream_t stream) {
    (void)in_sizes; (void)n_in; (void)out_size; (void)d_ws; (void)ws_size;
    const float* preds   = (const float*)d_in[0];
    const float* targets = (const float*)d_in[1];
    float* out = (float*)d_out;

    dist_kernel<<<dim3(4, 4, BB), 256, 0, stream>>>(preds, targets);
    scan_kernel<<<BB, 64, 0, stream>>>();
    fin_kernel<<<1, 128, 0, stream>>>(out);
}

// Round 12
// 120.628 us; speedup vs baseline: 10.9058x; 1.5841x over previous
//
#include <hip/hip_runtime.h>
#include <stdint.h>

#define BB 128
#define TT 256
#define DDIM 64
#define BIGF 1e10f
#define KE 144.2695040889f     // 1/(gamma*ln2)
#define GLN2 0.0069314718056f  // gamma*ln2 (R = R' * GLN2)

// [b][diag][row] layout (K-scaled). 512 diag slots; 511 = zeroed dummy.
// Invalid cells stay 0 (BSS) — harmless: R-select firewalls them.
__device__ float g_D[(size_t)BB * 512 * TT];
__device__ float g_shape[BB], g_sumE[BB], g_sumEw[BB];

__device__ __forceinline__ float ex2(float x){ float r; asm("v_exp_f32 %0, %1":"=v"(r):"v"(x)); return r; }
__device__ __forceinline__ float lg2(float x){ float r; asm("v_log_f32 %0, %1":"=v"(r):"v"(x)); return r; }
__device__ __forceinline__ float min3f(float a,float b,float c){ float r; asm("v_min3_f32 %0,%1,%2,%3":"=v"(r):"v"(a),"v"(b),"v"(c)); return r; }

// ---------------------------------------------------------------------------
// Kernel 1: pairwise squared distances (K-scaled), diagonal layout.
// ---------------------------------------------------------------------------
__global__ __launch_bounds__(256) void dist_kernel(const float* __restrict__ P,
                                                   const float* __restrict__ Q) {
    const int rt = blockIdx.x;
    const int ct = blockIdx.y;
    const int b  = blockIdx.z;
    const int tid = threadIdx.x;

    __shared__ float Pl[64][68];
    __shared__ float Tl[64][68];

    const float* Pbase = P + ((size_t)b * TT + rt * 64) * DDIM;
    const float* Qbase = Q + ((size_t)b * TT + ct * 64) * DDIM;

#pragma unroll
    for (int it = 0; it < 4; ++it) {
        int e = (tid + it * 256) * 4;
        int r = e >> 6;
        int k = e & 63;
        float4 pv = *reinterpret_cast<const float4*>(Pbase + e);
        float4 qv = *reinterpret_cast<const float4*>(Qbase + e);
        Pl[k + 0][r] = pv.x; Pl[k + 1][r] = pv.y; Pl[k + 2][r] = pv.z; Pl[k + 3][r] = pv.w;
        Tl[k + 0][r] = qv.x; Tl[k + 1][r] = qv.y; Tl[k + 2][r] = qv.z; Tl[k + 3][r] = qv.w;
    }
    __syncthreads();

    const int r0 = (tid >> 4) * 4;
    const int c0 = (tid & 15) * 4;

    float acc[4][4] = {};
#pragma unroll
    for (int k = 0; k < 64; ++k) {
        float4 p = *reinterpret_cast<const float4*>(&Pl[k][r0]);
        float4 t = *reinterpret_cast<const float4*>(&Tl[k][c0]);
        float pa[4] = {p.x, p.y, p.z, p.w};
        float ta[4] = {t.x, t.y, t.z, t.w};
#pragma unroll
        for (int a = 0; a < 4; ++a)
#pragma unroll
            for (int c = 0; c < 4; ++c) {
                float df = pa[a] - ta[c];
                acc[a][c] = fmaf(df, df, acc[a][c]);
            }
    }

    float* Dg = g_D + (size_t)b * 512 * TT;
#pragma unroll
    for (int a = 0; a < 4; ++a)
#pragma unroll
        for (int c = 0; c < 4; ++c) {
            int i = rt * 64 + r0 + a;
            int j = ct * 64 + c0 + c;
            Dg[(size_t)(i + j) * TT + i] = acc[a][c] * KE;
        }
    if (rt == 0 && ct == 0) Dg[(size_t)511 * TT + tid] = 0.0f;   // dummy diag
}

// ---------------------------------------------------------------------------
// Kernel 2: SINGLE-PASS soft-DTW (R' + path-sum accumulators H, G), spread
// across 4 skewed waves per batch. Wave w owns rows 64w..64w+63 (1 row/lane)
// and at phase p computes diag d = p - 16w. Cross-wave boundary (R,H,G) of
// lane63 goes through a 64-slot LDS ring; all 16 ring entries a group needs
// are written >= 1 barrier earlier, so they are STAGED at group start
// (no in-phase LDS latency). One __syncthreads per 16 phases. Branchless:
// validity via R-select only; (0,0) seeded by virtual pred z=0 (c1 trick).
// ---------------------------------------------------------------------------
__global__ __launch_bounds__(256) void scan_kernel() {
    const int b    = blockIdx.x;
    const int tid  = threadIdx.x;
    const int w    = tid >> 6;
    const int lane = tid & 63;
    const int row  = tid;                  // 64w + lane
    const bool lane0  = (lane == 0);
    const bool lane63 = (lane == 63);

    const float* Db = g_D + (size_t)b * 512 * TT;

    __shared__ float4 ring[64][5];         // [slot][wave]; col 4 = const {BIGF,0,0}
    for (int i = tid; i < 64 * 5; i += 256)
        ring[i / 5][i % 5] = make_float4(BIGF, 0.f, 0.f, 0.f);
    __syncthreads();

    const int rcol  = (w == 0) ? 4 : (w - 1);
    const int myoff = w << 4;

    // per-row state at diag d-1 / d-2
    float rp1 = BIGF, rp2 = BIGF, h1 = 0.f, h2 = 0.f, g1 = 0.f, g2 = 0.f;
    // shfl pipeline: row-1 values at d-1 (uX) and d-2 (uX2)
    float uR = BIGF, uR2 = BIGF, uH = 0.f, uH2 = 0.f, uG = 0.f, uG2 = 0.f;
    float c1  = 0.0f;                       // virtual (0,0) diag-pred; BIGF after phase 0
    float fwv = (float)(2 * row + 16 * w);  // i - j = 2*row - d = this - p

    auto LDD = [&](int d) -> float {
        int dc = d < 0 ? 0 : (d > 511 ? 511 : d);
        return Db[(size_t)dc * TT + row];
    };

    float dstA[16], dstB[16];
#pragma unroll
    for (int k = 0; k < 16; ++k) dstA[k] = LDD(k - myoff);

    float4 rstage[16];
    float4 rcarry = make_float4(BIGF, 0.f, 0.f, 0.f);

#pragma unroll 1
    for (int g = 0; g < 35; ++g) {          // 560 phases
        const int p0 = g << 4;
        // stage ring entries (boundary row at d-1 for each phase of this group)
#pragma unroll
        for (int k = 0; k < 16; ++k)
            rstage[k] = ring[(p0 + k - myoff - 1) & 63][rcol];
        // prefetch D for next group (consumed after next barrier)
#pragma unroll
        for (int k = 0; k < 16; ++k) dstB[k] = LDD(p0 + 16 + k - myoff);
        __builtin_amdgcn_sched_barrier(0);

#pragma unroll
        for (int k = 0; k < 16; ++k) {
            const int d = p0 + k - myoff;
            const float dcur = dstA[k];
            const float4 rb1 = rstage[k];                       // boundary @ d-1
            const float4 rb2 = (k == 0) ? rcarry : rstage[k - 1]; // boundary @ d-2
            // preds: up (i-1,j)@d-1, diag (i-1,j-1)@d-2, left (i,j-1)@d-1
            const float zu = lane0 ? rb1.x : uR;
            const float Hu = lane0 ? rb1.y : uH;
            const float Gu = lane0 ? rb1.z : uG;
            const float zd = lane0 ? fminf(rb2.x, c1) : uR2;
            const float Hd = lane0 ? rb2.y : uH2;
            const float Gd = lane0 ? rb2.z : uG2;
            const float m  = min3f(zd, zu, rp1);
            const float e1 = ex2(m - zd);      // diag weight (unnorm)
            const float e2 = ex2(m - zu);      // up
            const float e3 = ex2(m - rp1);     // left
            const float ss = e1 + e2 + e3;
            const float ri = __builtin_amdgcn_rcpf(ss);
            const float rv = dcur + (m - lg2(ss));
            const bool valid = (unsigned)(d - row) < 256u;      // 0 <= j < 256
            const float Rn = valid ? rv : BIGF;
            float ha = e3 * h1; ha = fmaf(e2, Hu, ha); ha = fmaf(e1, Hd, ha);
            const float Hn = fmaf(ri, ha, 1.0f);
            float ga = e3 * g1; ga = fmaf(e2, Gu, ga); ga = fmaf(e1, Gd, ga);
            const float Gn = fmaf(ri, ga, fwv * fwv);
            // boundary export for next diagonals
            const float nR = __shfl_up(Rn, 1);
            const float nH = __shfl_up(Hn, 1);
            const float nG = __shfl_up(Gn, 1);
            if (lane63) ring[d & 63][w] = make_float4(Rn, Hn, Gn, 0.f);
            // shift state
            rp2 = rp1; rp1 = Rn; h2 = h1; h1 = Hn; g2 = g1; g1 = Gn;
            uR2 = uR; uR = nR; uH2 = uH; uH = nH; uG2 = uG; uG = nG;
            c1 = BIGF;
            fwv -= 1.0f;
        }
        rcarry = rstage[15];
#pragma unroll
        for (int k = 0; k < 16; ++k) dstA[k] = dstB[k];
        __syncthreads();
    }

    // wave 3 lane 63 (row 255): after final phase (d=511 dummy), d-1 state = diag 510
    if (tid == 255) {
        g_shape[b] = rp2;    // R'(255,255)
        g_sumE[b]  = h2;     // sum(E)
        g_sumEw[b] = g2;     // sum(E * (i-j)^2)
    }
}

// ---------------------------------------------------------------------------
// Kernel 3: finalize scalar loss.
// ---------------------------------------------------------------------------
__global__ __launch_bounds__(128) void fin_kernel(float* __restrict__ out) {
    __shared__ float rs[128];
    __shared__ float rt2[128];
    const int b = threadIdx.x;

    const float shape = g_shape[b] * GLN2 * (1.0f / (float)TT);

    const float sE  = g_sumE[b]  * (1.0f / (float)TT);
    const float sEw = g_sumEw[b] * (1.0f / (float)TT) * (1.0f / (255.0f * 255.0f));
    const float temporal = sEw / fmaxf(sE, 1e-8f);

    rs[b]  = shape;
    rt2[b] = temporal;
    __syncthreads();
    for (int s = 64; s > 0; s >>= 1) {
        if (b < s) { rs[b] += rs[b + s]; rt2[b] += rt2[b + s]; }
        __syncthreads();
    }
    if (b == 0) {
        out[0] = 0.5f * (rs[0] * (1.0f / (float)BB)) + 0.5f * (rt2[0] * (1.0f / (float)BB));
    }
}

extern "C" void kernel_launch(void* const* d_in, const int* in_sizes, int n_in,
                              void* d_out, int out_size, void* d_ws, size_t ws_size,
                              hipStream_t stream) {
    (void)in_sizes; (void)n_in; (void)out_size; (void)d_ws; (void)ws_size;
    const float* preds   = (const float*)d_in[0];
    const float* targets = (const float*)d_in[1];
    float* out = (float*)d_out;

    dist_kernel<<<dim3(4, 4, BB), 256, 0, stream>>>(preds, targets);
    scan_kernel<<<BB, 256, 0, stream>>>();
    fin_kernel<<<1, 128, 0, stream>>>(out);
}